// Round 3
// baseline (526.294 us; speedup 1.0000x reference)
//
#include <hip/hip_runtime.h>

// DynamicRouting: votes [B=32, NIN=2048, NOUT=64, ATOMS=16] fp32, 3 routing iters.
// 3 streaming passes are structural (pose = full n_in reduction). Byte-count
// optimization: pass 0 reads fp32 votes (256 MB), computes preact0 (c=1/64),
// and writes a bf16 copy (128 MB) into d_ws; passes 1-2 read the bf16 copy
// (128 MB each, L3-resident). Lane = out-capsule; softmax over outs = 6-level
// shuffle butterfly (no max-subtract: |logit| <= ~16, exp can't overflow).
// Per-block partial sums (no atomics, no memset); squash_reduce folds the
// 64-chunk reduction + squash + pose_accum update into one tiny kernel.

#define NB 32
#define NIN 2048
#define NOUT 64
#define ATOMS 16
#define EPSF 1e-9f

#define ROWS_PER_WAVE 8
#define WAVES_PER_BLOCK 4
#define ROWS_PER_BLOCK (ROWS_PER_WAVE * WAVES_PER_BLOCK) // 32
#define CHUNKS (NIN / ROWS_PER_BLOCK)                    // 64
#define RBATCH 4

__device__ __forceinline__ unsigned pack2_bf16(float lo, float hi) {
    unsigned ul = __float_as_uint(lo);
    unsigned uh = __float_as_uint(hi);
    ul = (ul + 0x7fffu + ((ul >> 16) & 1u)) >> 16;         // RNE round to bf16
    uh = (uh + 0x7fffu + ((uh >> 16) & 1u)) & 0xffff0000u;
    return ul | uh;
}

// ---- pass 0: fp32 read, uniform c = 1/64, emit bf16 votes + partials ----
__global__ __launch_bounds__(256, 4) void route_pass0(
    const float* __restrict__ votes,
    uint4* __restrict__ votes_bf16,
    float* __restrict__ partials)
{
    const int b     = blockIdx.x / CHUNKS;
    const int chunk = blockIdx.x % CHUNKS;
    const int wave  = threadIdx.x >> 6;
    const int lane  = threadIdx.x & 63; // out-capsule index

    float acc[ATOMS];
#pragma unroll
    for (int a = 0; a < ATOMS; ++a) acc[a] = 0.0f;

    const int in0 = chunk * ROWS_PER_BLOCK + wave * ROWS_PER_WAVE;
    const float4* vrow = reinterpret_cast<const float4*>(votes)
                       + ((size_t)(b * NIN + in0) * NOUT + lane) * 4;
    uint4* brow = votes_bf16 + ((size_t)(b * NIN + in0) * NOUT + lane) * 2;

    for (int r0 = 0; r0 < ROWS_PER_WAVE; r0 += RBATCH) {
        float4 c[RBATCH][4];
#pragma unroll
        for (int r = 0; r < RBATCH; ++r) {
            const float4* vp = vrow + (size_t)(r0 + r) * (NOUT * 4);
            c[r][0] = vp[0]; c[r][1] = vp[1]; c[r][2] = vp[2]; c[r][3] = vp[3];
        }
#pragma unroll
        for (int r = 0; r < RBATCH; ++r) {
            const float* v = reinterpret_cast<const float*>(&c[r][0]);
#pragma unroll
            for (int a = 0; a < ATOMS; ++a) acc[a] += v[a];
            uint4 p0, p1;
            p0.x = pack2_bf16(v[0],  v[1]);  p0.y = pack2_bf16(v[2],  v[3]);
            p0.z = pack2_bf16(v[4],  v[5]);  p0.w = pack2_bf16(v[6],  v[7]);
            p1.x = pack2_bf16(v[8],  v[9]);  p1.y = pack2_bf16(v[10], v[11]);
            p1.z = pack2_bf16(v[12], v[13]); p1.w = pack2_bf16(v[14], v[15]);
            uint4* bp = brow + (size_t)(r0 + r) * (NOUT * 2);
            bp[0] = p0; bp[1] = p1;
        }
    }
#pragma unroll
    for (int a = 0; a < ATOMS; ++a) acc[a] *= (1.0f / 64.0f);

    __shared__ float red[WAVES_PER_BLOCK * NOUT * ATOMS]; // 16 KiB
#pragma unroll
    for (int a = 0; a < ATOMS; ++a)
        red[(wave * NOUT + lane) * ATOMS + a] = acc[a];
    __syncthreads();

    float* pblock = partials + ((size_t)(b * CHUNKS + chunk) << 10);
    for (int idx = threadIdx.x; idx < NOUT * ATOMS; idx += 256) {
        pblock[idx] = red[idx] + red[NOUT * ATOMS + idx]
                    + red[2 * NOUT * ATOMS + idx] + red[3 * NOUT * ATOMS + idx];
    }
}

// ---- passes 1-2: bf16 read, logits = <v, pose_accum>, softmax, partials ----
__global__ __launch_bounds__(256, 4) void route_passN(
    const uint4* __restrict__ votes_bf16,
    const float* __restrict__ pose_accum,
    float* __restrict__ partials)
{
    const int b     = blockIdx.x / CHUNKS;
    const int chunk = blockIdx.x % CHUNKS;
    const int wave  = threadIdx.x >> 6;
    const int lane  = threadIdx.x & 63;

    float pose[ATOMS];
    {
        const float4* p4 = reinterpret_cast<const float4*>(pose_accum) + (b * NOUT + lane) * 4;
        float4 q0 = p4[0], q1 = p4[1], q2 = p4[2], q3 = p4[3];
        pose[0]=q0.x; pose[1]=q0.y; pose[2]=q0.z; pose[3]=q0.w;
        pose[4]=q1.x; pose[5]=q1.y; pose[6]=q1.z; pose[7]=q1.w;
        pose[8]=q2.x; pose[9]=q2.y; pose[10]=q2.z; pose[11]=q2.w;
        pose[12]=q3.x; pose[13]=q3.y; pose[14]=q3.z; pose[15]=q3.w;
    }

    float acc[ATOMS];
#pragma unroll
    for (int a = 0; a < ATOMS; ++a) acc[a] = 0.0f;

    const int in0 = chunk * ROWS_PER_BLOCK + wave * ROWS_PER_WAVE;
    const uint4* brow = votes_bf16 + ((size_t)(b * NIN + in0) * NOUT + lane) * 2;

    for (int r0 = 0; r0 < ROWS_PER_WAVE; r0 += RBATCH) {
        uint4 raw[RBATCH][2];
#pragma unroll
        for (int r = 0; r < RBATCH; ++r) {
            const uint4* bp = brow + (size_t)(r0 + r) * (NOUT * 2);
            raw[r][0] = bp[0]; raw[r][1] = bp[1];
        }
        float v[RBATCH][ATOMS];
#pragma unroll
        for (int r = 0; r < RBATCH; ++r) {
            const unsigned* u = reinterpret_cast<const unsigned*>(&raw[r][0]);
#pragma unroll
            for (int k = 0; k < 8; ++k) {
                v[r][2*k]   = __uint_as_float(u[k] << 16);
                v[r][2*k+1] = __uint_as_float(u[k] & 0xffff0000u);
            }
        }
        float e[RBATCH], s[RBATCH];
#pragma unroll
        for (int r = 0; r < RBATCH; ++r) {
            float logit = 0.0f;
#pragma unroll
            for (int a = 0; a < ATOMS; ++a) logit = fmaf(v[r][a], pose[a], logit);
            e[r] = __expf(logit);   // |logit| <= ~16: no overflow risk
            s[r] = e[r];
        }
#pragma unroll
        for (int mask = 32; mask >= 1; mask >>= 1) {
#pragma unroll
            for (int r = 0; r < RBATCH; ++r)
                s[r] += __shfl_xor(s[r], mask, 64);
        }
#pragma unroll
        for (int r = 0; r < RBATCH; ++r) {
            float cc = e[r] / s[r];
#pragma unroll
            for (int a = 0; a < ATOMS; ++a) acc[a] = fmaf(cc, v[r][a], acc[a]);
        }
    }

    __shared__ float red[WAVES_PER_BLOCK * NOUT * ATOMS];
#pragma unroll
    for (int a = 0; a < ATOMS; ++a)
        red[(wave * NOUT + lane) * ATOMS + a] = acc[a];
    __syncthreads();

    float* pblock = partials + ((size_t)(b * CHUNKS + chunk) << 10);
    for (int idx = threadIdx.x; idx < NOUT * ATOMS; idx += 256) {
        pblock[idx] = red[idx] + red[NOUT * ATOMS + idx]
                    + red[2 * NOUT * ATOMS + idx] + red[3 * NOUT * ATOMS + idx];
    }
}

// ---- reduce 64 chunk-partials, squash; mode 0: pose_accum = pose,
//      mode 1: pose_accum += pose, mode 2: write d_out (pose + prob) ----
__global__ __launch_bounds__(256) void squash_reduce(
    const float* __restrict__ partials,
    float* __restrict__ pose_accum,
    float* __restrict__ d_out,
    int mode)
{
    int gid = blockIdx.x * 256 + threadIdx.x;  // < NB*NOUT*ATOMS = 32768
    int b  = gid >> 10;
    int oa = gid & 1023;
    const float* p = partials + ((size_t)b << 16) + oa;
    float s0 = 0.0f, s1 = 0.0f, s2 = 0.0f, s3 = 0.0f;
#pragma unroll
    for (int c = 0; c < CHUNKS; c += 4) {
        s0 += p[(c + 0) << 10];
        s1 += p[(c + 1) << 10];
        s2 += p[(c + 2) << 10];
        s3 += p[(c + 3) << 10];
    }
    float s = (s0 + s1) + (s2 + s3);

    float sq = s * s;
#pragma unroll
    for (int mask = 1; mask < ATOMS; mask <<= 1)
        sq += __shfl_xor(sq, mask, 64);
    float norm = sqrtf(sq + EPSF);
    float f = (sq / (1.0f + sq)) / norm;
    float pse = f * s;
    if (mode == 0) {
        pose_accum[gid] = pse;
    } else if (mode == 1) {
        pose_accum[gid] += pse;
    } else {
        d_out[gid] = pse;
        if ((gid & (ATOMS - 1)) == 0) {
            float psq = f * f * sq; // sum over atoms of pose^2
            d_out[NB * NOUT * ATOMS + (gid >> 4)] = sqrtf(psq + EPSF);
        }
    }
}

extern "C" void kernel_launch(void* const* d_in, const int* in_sizes, int n_in,
                              void* d_out, int out_size, void* d_ws, size_t ws_size,
                              hipStream_t stream) {
    const float* votes = (const float*)d_in[0];
    float* out = (float*)d_out;

    // d_ws layout (1 GiB available):
    //   pose_accum : 32768 floats (128 KiB)
    //   partials   : NB*CHUNKS*1024 = 2M floats (8 MiB)
    //   votes_bf16 : 32*2048*64*16 bf16 = 128 MiB
    float* pose_accum = (float*)d_ws;
    float* partials   = pose_accum + NB * NOUT * ATOMS;
    uint4* votes_bf16 = (uint4*)(partials + (size_t)NB * CHUNKS * NOUT * ATOMS);

    dim3 blk(256);
    dim3 grid_route(NB * CHUNKS);            // 2048 blocks
    dim3 grid_sq(NB * NOUT * ATOMS / 256);   // 128 blocks

    // iter 0: c = 1/64 uniform; also emits bf16 votes copy
    route_pass0<<<grid_route, blk, 0, stream>>>(votes, votes_bf16, partials);
    squash_reduce<<<grid_sq, blk, 0, stream>>>(partials, pose_accum, nullptr, 0);

    // iter 1: logits = <votes, pose0>
    route_passN<<<grid_route, blk, 0, stream>>>(votes_bf16, pose_accum, partials);
    squash_reduce<<<grid_sq, blk, 0, stream>>>(partials, pose_accum, nullptr, 1);

    // iter 2: logits = <votes, pose0+pose1>
    route_passN<<<grid_route, blk, 0, stream>>>(votes_bf16, pose_accum, partials);
    squash_reduce<<<grid_sq, blk, 0, stream>>>(partials, nullptr, out, 2);
}

// Round 4
// 446.440 us; speedup vs baseline: 1.1789x; 1.1789x over previous
//
#include <hip/hip_runtime.h>

// DynamicRouting: votes [B=32, NIN=2048, NOUT=64, ATOMS=16] fp32, 3 iters.
// 3 streaming fp32 passes (pose = full n_in reduction per iter => structural).
// KEY CHANGE (R4): fully-coalesced lane mapping. A row (b,in) is 4 KB; load
// instruction j has lane i read float4 at (j*64+i)*16 -> 1 KB contiguous per
// instruction (16 cache lines), vs the previous lane=out mapping which put
// lanes at stride 64 B (64 distinct lines per instruction -> request-rate
// limited, which is why R1's and R2's occupancy changes tied at 458 us).
// Lane i holds atoms [4q..4q+3] (q=lane&3) of out o_j = j*16 + (lane>>2).
// logit: 4 in-lane FMAs + quad butterfly (masks 1,2); softmax denom:
// butterfly masks 4,8,16,32. Per-block partials (no atomics/memsets);
// squash_reduce folds chunk-reduction + squash + pose_accum update.

#define NB 32
#define NIN 2048
#define NOUT 64
#define ATOMS 16
#define EPSF 1e-9f

#define ROWS_PER_WAVE 8
#define WAVES_PER_BLOCK 4
#define ROWS_PER_BLOCK (ROWS_PER_WAVE * WAVES_PER_BLOCK) // 32
#define CHUNKS (NIN / ROWS_PER_BLOCK)                    // 64
#define RBATCH 2

template <int USE_POSE>
__global__ __launch_bounds__(256, 4) void route_pass(
    const float4* __restrict__ votes4,
    const float4* __restrict__ pose_accum4,
    float4* __restrict__ partials4)
{
    const int b     = blockIdx.x / CHUNKS;
    const int chunk = blockIdx.x % CHUNKS;
    const int wave  = threadIdx.x >> 6;
    const int lane  = threadIdx.x & 63;

    // lane's pose fragments: atoms [4q..4q+3] of outs o_j = j*16 + (lane>>2)
    float4 pse[4];
    if (USE_POSE) {
#pragma unroll
        for (int j = 0; j < 4; ++j)
            pse[j] = pose_accum4[(b * NOUT + j * 16 + (lane >> 2)) * 4 + (lane & 3)];
    }

    float4 acc[4];
#pragma unroll
    for (int j = 0; j < 4; ++j) acc[j] = make_float4(0.f, 0.f, 0.f, 0.f);

    const int in0 = chunk * ROWS_PER_BLOCK + wave * ROWS_PER_WAVE;
    const float4* vrow = votes4 + (size_t)(b * NIN + in0) * 256 + lane;

    for (int r0 = 0; r0 < ROWS_PER_WAVE; r0 += RBATCH) {
        float4 v[RBATCH][4];
#pragma unroll
        for (int r = 0; r < RBATCH; ++r) {
            const float4* vp = vrow + (size_t)(r0 + r) * 256;
#pragma unroll
            for (int j = 0; j < 4; ++j) v[r][j] = vp[j * 64]; // 1 KB contiguous / instr
        }

        if (USE_POSE) {
            float lg[RBATCH][4];
#pragma unroll
            for (int r = 0; r < RBATCH; ++r)
#pragma unroll
                for (int j = 0; j < 4; ++j) {
                    float d = v[r][j].x * pse[j].x;
                    d = fmaf(v[r][j].y, pse[j].y, d);
                    d = fmaf(v[r][j].z, pse[j].z, d);
                    d = fmaf(v[r][j].w, pse[j].w, d);
                    lg[r][j] = d;
                }
            // quad-reduce (atoms split across lanes q=0..3)
#pragma unroll
            for (int mask = 1; mask <= 2; mask <<= 1)
#pragma unroll
                for (int r = 0; r < RBATCH; ++r)
#pragma unroll
                    for (int j = 0; j < 4; ++j)
                        lg[r][j] += __shfl_xor(lg[r][j], mask, 64);

            float e[RBATCH][4], s[RBATCH];
#pragma unroll
            for (int r = 0; r < RBATCH; ++r) {
                float t = 0.f;
#pragma unroll
                for (int j = 0; j < 4; ++j) { e[r][j] = __expf(lg[r][j]); t += e[r][j]; }
                s[r] = t;
            }
            // sum over the 16 quad-groups -> full softmax denom over 64 outs
#pragma unroll
            for (int mask = 4; mask <= 32; mask <<= 1)
#pragma unroll
                for (int r = 0; r < RBATCH; ++r)
                    s[r] += __shfl_xor(s[r], mask, 64);

#pragma unroll
            for (int r = 0; r < RBATCH; ++r) {
                float inv = __frcp_rn(s[r]);
#pragma unroll
                for (int j = 0; j < 4; ++j) {
                    float c = e[r][j] * inv;
                    acc[j].x = fmaf(c, v[r][j].x, acc[j].x);
                    acc[j].y = fmaf(c, v[r][j].y, acc[j].y);
                    acc[j].z = fmaf(c, v[r][j].z, acc[j].z);
                    acc[j].w = fmaf(c, v[r][j].w, acc[j].w);
                }
            }
        } else {
#pragma unroll
            for (int r = 0; r < RBATCH; ++r)
#pragma unroll
                for (int j = 0; j < 4; ++j) {
                    acc[j].x += v[r][j].x; acc[j].y += v[r][j].y;
                    acc[j].z += v[r][j].z; acc[j].w += v[r][j].w;
                }
        }
    }
    if (!USE_POSE) {
#pragma unroll
        for (int j = 0; j < 4; ++j) {
            acc[j].x *= (1.f / 64.f); acc[j].y *= (1.f / 64.f);
            acc[j].z *= (1.f / 64.f); acc[j].w *= (1.f / 64.f);
        }
    }

    // block reduction: lane's acc[j] lands at float4 index j*64+lane of the
    // standard [out][atom] layout -- perfectly regular LDS addressing.
    __shared__ float4 red4[WAVES_PER_BLOCK * 256]; // 16 KiB
#pragma unroll
    for (int j = 0; j < 4; ++j)
        red4[wave * 256 + j * 64 + lane] = acc[j];
    __syncthreads();

    float4* pblock4 = partials4 + ((size_t)(b * CHUNKS + chunk) << 8);
    {
        int idx = threadIdx.x; // 256 threads x 1 float4 = 1024 floats
        float4 a = red4[idx], b2 = red4[256 + idx], c = red4[512 + idx], d = red4[768 + idx];
        float4 t;
        t.x = (a.x + b2.x) + (c.x + d.x);
        t.y = (a.y + b2.y) + (c.y + d.y);
        t.z = (a.z + b2.z) + (c.z + d.z);
        t.w = (a.w + b2.w) + (c.w + d.w);
        pblock4[idx] = t;
    }
}

// reduce 64 chunk-partials, squash; mode 0: pose_accum = pose,
// mode 1: pose_accum += pose, mode 2: write d_out (pose + prob)
__global__ __launch_bounds__(256) void squash_reduce(
    const float* __restrict__ partials,
    float* __restrict__ pose_accum,
    float* __restrict__ d_out,
    int mode)
{
    int gid = blockIdx.x * 256 + threadIdx.x;  // < NB*NOUT*ATOMS = 32768
    int b  = gid >> 10;
    int oa = gid & 1023;
    const float* p = partials + ((size_t)b << 16) + oa;
    float s0 = 0.f, s1 = 0.f, s2 = 0.f, s3 = 0.f;
#pragma unroll
    for (int c = 0; c < CHUNKS; c += 4) {
        s0 += p[(c + 0) << 10];
        s1 += p[(c + 1) << 10];
        s2 += p[(c + 2) << 10];
        s3 += p[(c + 3) << 10];
    }
    float s = (s0 + s1) + (s2 + s3);

    float sq = s * s;
#pragma unroll
    for (int mask = 1; mask < ATOMS; mask <<= 1)
        sq += __shfl_xor(sq, mask, 64);
    float norm = sqrtf(sq + EPSF);
    float f = (sq / (1.0f + sq)) / norm;
    float pse = f * s;
    if (mode == 0) {
        pose_accum[gid] = pse;
    } else if (mode == 1) {
        pose_accum[gid] += pse;
    } else {
        d_out[gid] = pse;
        if ((gid & (ATOMS - 1)) == 0) {
            float psq = f * f * sq; // sum over atoms of pose^2
            d_out[NB * NOUT * ATOMS + (gid >> 4)] = sqrtf(psq + EPSF);
        }
    }
}

extern "C" void kernel_launch(void* const* d_in, const int* in_sizes, int n_in,
                              void* d_out, int out_size, void* d_ws, size_t ws_size,
                              hipStream_t stream) {
    const float4* votes4 = (const float4*)d_in[0];
    float* out = (float*)d_out;

    // d_ws: pose_accum (128 KiB) | partials (8 MiB)
    float* pose_accum = (float*)d_ws;
    float* partials   = pose_accum + NB * NOUT * ATOMS;

    dim3 blk(256);
    dim3 grid_route(NB * CHUNKS);            // 2048 blocks
    dim3 grid_sq(NB * NOUT * ATOMS / 256);   // 128 blocks

    // iter 0: c = 1/64 uniform
    route_pass<0><<<grid_route, blk, 0, stream>>>(votes4, nullptr, (float4*)partials);
    squash_reduce<<<grid_sq, blk, 0, stream>>>(partials, pose_accum, nullptr, 0);

    // iter 1: logits = <votes, pose0>
    route_pass<1><<<grid_route, blk, 0, stream>>>(votes4, (const float4*)pose_accum, (float4*)partials);
    squash_reduce<<<grid_sq, blk, 0, stream>>>(partials, pose_accum, nullptr, 1);

    // iter 2: logits = <votes, pose0+pose1>
    route_pass<1><<<grid_route, blk, 0, stream>>>(votes4, (const float4*)pose_accum, (float4*)partials);
    squash_reduce<<<grid_sq, blk, 0, stream>>>(partials, nullptr, out, 2);
}